// Round 4
// baseline (473.484 us; speedup 1.0000x reference)
//
#include <hip/hip_runtime.h>
#include <hip/hip_bf16.h>
#include <cstddef>

#define D 128

__global__ void k_zero(int* __restrict__ p, int n) {
  int i = blockIdx.x * blockDim.x + threadIdx.x;
  if (i < n) p[i] = 0;
}

__global__ void k_deg_count(const int* __restrict__ dst, int e, int* __restrict__ cnt) {
  int i = blockIdx.x * blockDim.x + threadIdx.x;
  if (i < e) atomicAdd(&cnt[dst[i]], 1);
}

// exclusive scan of cnt (1024/block) -> rowptr, block sums; fused dinv = rsqrt(cnt+1)
__global__ __launch_bounds__(256) void k_scan1(const int* __restrict__ cnt,
                                               int* __restrict__ rowptr,
                                               int* __restrict__ bsums,
                                               float* __restrict__ dinv, int n) {
  __shared__ int sdata[256];
  const int tid = threadIdx.x;
  const int idx = blockIdx.x * 1024 + tid * 4;
  int v[4], s = 0;
#pragma unroll
  for (int u = 0; u < 4; ++u) {
    int c = 0;
    if (idx + u < n) {
      c = cnt[idx + u];
      dinv[idx + u] = fminf(rsqrtf((float)(c + 1)), 1.0e6f);
    }
    v[u] = s; s += c;
  }
  sdata[tid] = s;
  __syncthreads();
  for (int off = 1; off < 256; off <<= 1) {
    int t = (tid >= off) ? sdata[tid - off] : 0;
    __syncthreads();
    sdata[tid] += t;
    __syncthreads();
  }
  const int excl = (tid > 0) ? sdata[tid - 1] : 0;
#pragma unroll
  for (int u = 0; u < 4; ++u)
    if (idx + u < n) rowptr[idx + u] = excl + v[u];
  if (tid == 255) bsums[blockIdx.x] = sdata[255];
}

__global__ __launch_bounds__(256) void k_scan2(int* __restrict__ bsums, int nb) {
  __shared__ int sdata[256];
  const int tid = threadIdx.x;
  sdata[tid] = (tid < nb) ? bsums[tid] : 0;
  __syncthreads();
  for (int off = 1; off < 256; off <<= 1) {
    int t = (tid >= off) ? sdata[tid - off] : 0;
    __syncthreads();
    sdata[tid] += t;
    __syncthreads();
  }
  const int excl = (tid > 0) ? sdata[tid - 1] : 0;
  if (tid < nb) bsums[tid] = excl;
}

__global__ void k_scan3(int* __restrict__ rowptr, const int* __restrict__ bsums, int n) {
  int i = blockIdx.x * blockDim.x + threadIdx.x;
  if (i < n) rowptr[i] += bsums[i >> 10];
}

__global__ void k_fill(const int* __restrict__ src, const int* __restrict__ dst,
                       const int* __restrict__ rowptr, int* __restrict__ cursor,
                       int* __restrict__ srcs, int e) {
  int i = blockIdx.x * blockDim.x + threadIdx.x;
  if (i < e) {
    const int d = dst[i];
    const int pos = rowptr[d] + atomicAdd(&cursor[d], 1);
    srcs[pos] = src[i];
  }
}

// g(bf16) = (x @ W^T + b) * dinv[r].  BK=32 chunks, single LDS buffer + register
// prefetch of next chunk (global-load latency hides under FMA). LDS = 36.9 KB ->
// 2+ blocks/CU (vs 132 KB, 1 block/CU before).
__global__ __launch_bounds__(256) void k_gemm(
    const float* __restrict__ x, const float* __restrict__ W,
    const float* __restrict__ bias, const float* __restrict__ dinv,
    __hip_bfloat16* __restrict__ g, int n) {
  __shared__ float Ws[128][36];  // [col j][k] pad->36: banks spread, 16B-aligned rows
  __shared__ float xs[128][36];  // [row r][k]
  const int tid = threadIdx.x;
  const int row0 = blockIdx.x * 128;

  auto ldg_chunk = [&](int k0, float4 wp[4], float4 xp[4]) {
#pragma unroll
    for (int u = 0; u < 4; ++u) {
      const int f = tid + 256 * u;   // 0..1023
      const int j = f >> 3;          // 0..127
      const int kq = (f & 7) << 2;   // 0,4,..,28
      wp[u] = *reinterpret_cast<const float4*>(&W[(size_t)j * D + k0 + kq]);
      const int r = row0 + j;
      xp[u] = (r < n) ? *reinterpret_cast<const float4*>(&x[(size_t)r * D + k0 + kq])
                      : make_float4(0.f, 0.f, 0.f, 0.f);
    }
  };
  auto sts_chunk = [&](const float4 wp[4], const float4 xp[4]) {
#pragma unroll
    for (int u = 0; u < 4; ++u) {
      const int f = tid + 256 * u;
      const int j = f >> 3;
      const int kq = (f & 7) << 2;
      *reinterpret_cast<float4*>(&Ws[j][kq]) = wp[u];
      *reinterpret_cast<float4*>(&xs[j][kq]) = xp[u];
    }
  };

  float4 wp[4], xp[4];
  ldg_chunk(0, wp, xp);
  sts_chunk(wp, xp);
  __syncthreads();

  const int jc = tid & 15;  // cols jc+16*dj
  const int rg = tid >> 4;  // rows rg+16*i
  float acc[8][8];
#pragma unroll
  for (int i = 0; i < 8; ++i)
#pragma unroll
    for (int dj = 0; dj < 8; ++dj) acc[i][dj] = 0.f;

  for (int kc = 0; kc < 4; ++kc) {
    if (kc < 3) ldg_chunk((kc + 1) * 32, wp, xp);  // prefetch next chunk to regs
#pragma unroll
    for (int k = 0; k < 32; k += 4) {
      float4 wv[8];
#pragma unroll
      for (int dj = 0; dj < 8; ++dj)
        wv[dj] = *reinterpret_cast<const float4*>(&Ws[jc + 16 * dj][k]);
#pragma unroll
      for (int i = 0; i < 8; ++i) {
        const float4 xv = *reinterpret_cast<const float4*>(&xs[rg + 16 * i][k]);
#pragma unroll
        for (int dj = 0; dj < 8; ++dj) {
          acc[i][dj] += xv.x * wv[dj].x;
          acc[i][dj] += xv.y * wv[dj].y;
          acc[i][dj] += xv.z * wv[dj].z;
          acc[i][dj] += xv.w * wv[dj].w;
        }
      }
    }
    __syncthreads();
    if (kc < 3) { sts_chunk(wp, xp); __syncthreads(); }
  }

#pragma unroll
  for (int i = 0; i < 8; ++i) {
    const int r = row0 + rg + 16 * i;
    if (r < n) {
      const float s = dinv[r];
#pragma unroll
      for (int dj = 0; dj < 8; ++dj) {
        const int j = jc + 16 * dj;
        g[(size_t)r * D + j] = __float2bfloat16((acc[i][dj] + bias[j]) * s);
      }
    }
  }
}

// one wave per node: out[v] = dinv[v]*(g[v] + sum g[s]); g rows are bf16 (256B),
// lane reads one uint (2 bf16) -> 256B/wave coalesced gather.
__global__ __launch_bounds__(256) void k_accum(
    const int* __restrict__ rowptr, const int* __restrict__ cnt,
    const int* __restrict__ srcs, const unsigned int* __restrict__ g2,
    const float* __restrict__ dinv, float* __restrict__ out, int n) {
  const int w = (int)(((size_t)blockIdx.x * 256 + threadIdx.x) >> 6);
  const int lane = threadIdx.x & 63;
  if (w >= n) return;
  const int beg = rowptr[w];
  const int num = cnt[w];
  const unsigned int v = g2[(size_t)w * 64 + lane];  // self-loop term
  float ax = __uint_as_float(v << 16);
  float ay = __uint_as_float(v & 0xffff0000u);
  int k = 0;
  for (; k + 8 <= num; k += 8) {
    unsigned int t[8];
#pragma unroll
    for (int u = 0; u < 8; ++u)
      t[u] = g2[(size_t)srcs[beg + k + u] * 64 + lane];
#pragma unroll
    for (int u = 0; u < 8; ++u) {
      ax += __uint_as_float(t[u] << 16);
      ay += __uint_as_float(t[u] & 0xffff0000u);
    }
  }
  for (; k < num; ++k) {
    const unsigned int t = g2[(size_t)srcs[beg + k] * 64 + lane];
    ax += __uint_as_float(t << 16);
    ay += __uint_as_float(t & 0xffff0000u);
  }
  const float dv = dinv[w];
  ((float2*)out)[(size_t)w * 64 + lane] = make_float2(ax * dv, ay * dv);
}

extern "C" void kernel_launch(void* const* d_in, const int* in_sizes, int n_in,
                              void* d_out, int out_size, void* d_ws, size_t ws_size,
                              hipStream_t stream) {
  const float* x = (const float*)d_in[0];
  const int* ei = (const int*)d_in[1];
  const float* W = (const float*)d_in[2];
  const float* b = (const float*)d_in[3];
  float* out = (float*)d_out;
  const int n = in_sizes[0] / D;
  const int e = in_sizes[1] / 2;
  const int* src = ei;      // edge_index[0]
  const int* dst = ei + e;  // edge_index[1]

  char* ws = (char*)d_ws;
  const size_t nb = ((size_t)n * 4 + 255) / 256 * 256;
  const size_t eb = ((size_t)e * 4 + 255) / 256 * 256;
  int* rowptr = (int*)ws;                          // n ints
  int* cnt = (int*)(ws + nb);                      // n ints (in-degree)
  float* dinv = (float*)(ws + 2 * nb);             // n floats
  int* cursor = (int*)(ws + 3 * nb);               // n ints
  int* bsums = (int*)(ws + 4 * nb);                // <=512 ints
  int* srcs = (int*)(ws + 4 * nb + 4096);          // e ints
  __hip_bfloat16* g = (__hip_bfloat16*)(ws + 4 * nb + 4096 + eb);  // n*128 bf16

  const int nscan = (n + 1023) / 1024;

  k_zero<<<(n + 255) / 256, 256, 0, stream>>>(cnt, n);
  k_deg_count<<<(e + 255) / 256, 256, 0, stream>>>(dst, e, cnt);
  k_scan1<<<nscan, 256, 0, stream>>>(cnt, rowptr, bsums, dinv, n);
  k_scan2<<<1, 256, 0, stream>>>(bsums, nscan);
  k_scan3<<<(n + 255) / 256, 256, 0, stream>>>(rowptr, bsums, n);
  k_zero<<<(n + 255) / 256, 256, 0, stream>>>(cursor, n);
  k_gemm<<<(n + 127) / 128, 256, 0, stream>>>(x, W, b, dinv, g, n);
  k_fill<<<(e + 255) / 256, 256, 0, stream>>>(src, dst, rowptr, cursor, srcs, e);
  // one 64-lane wave per node -> n/4 blocks of 256 threads
  k_accum<<<(n + 3) / 4, 256, 0, stream>>>(rowptr, cnt, srcs, (const unsigned int*)g,
                                           dinv, out, n);
}

// Round 5
// 279.968 us; speedup vs baseline: 1.6912x; 1.6912x over previous
//
#include <hip/hip_runtime.h>
#include <hip/hip_bf16.h>
#include <cstddef>

#define D 128

typedef __attribute__((ext_vector_type(8))) short bf16x8;
typedef __attribute__((ext_vector_type(16))) float f32x16;

static __device__ __forceinline__ unsigned short f2bf(float f) {
  return __builtin_bit_cast(unsigned short, __float2bfloat16(f));
}

__global__ void k_zero(int* __restrict__ p, int n) {
  int i = blockIdx.x * blockDim.x + threadIdx.x;
  if (i < n) p[i] = 0;
}

__global__ void k_deg_count(const int* __restrict__ dst, int e, int* __restrict__ cnt) {
  int i = blockIdx.x * blockDim.x + threadIdx.x;
  if (i < e) atomicAdd(&cnt[dst[i]], 1);
}

// exclusive scan of cnt (1024/block) -> rowptr + block sums; fused dinv
__global__ __launch_bounds__(256) void k_scan1(const int* __restrict__ cnt,
                                               int* __restrict__ rowptr,
                                               int* __restrict__ bsums,
                                               float* __restrict__ dinv, int n) {
  __shared__ int sdata[256];
  const int tid = threadIdx.x;
  const int idx = blockIdx.x * 1024 + tid * 4;
  int v[4], s = 0;
#pragma unroll
  for (int u = 0; u < 4; ++u) {
    int c = 0;
    if (idx + u < n) {
      c = cnt[idx + u];
      dinv[idx + u] = fminf(rsqrtf((float)(c + 1)), 1.0e6f);
    }
    v[u] = s; s += c;
  }
  sdata[tid] = s;
  __syncthreads();
  for (int off = 1; off < 256; off <<= 1) {
    int t = (tid >= off) ? sdata[tid - off] : 0;
    __syncthreads();
    sdata[tid] += t;
    __syncthreads();
  }
  const int excl = (tid > 0) ? sdata[tid - 1] : 0;
#pragma unroll
  for (int u = 0; u < 4; ++u)
    if (idx + u < n) rowptr[idx + u] = excl + v[u];
  if (tid == 255) bsums[blockIdx.x] = sdata[255];
}

__global__ __launch_bounds__(256) void k_scan2(int* __restrict__ bsums, int nb) {
  __shared__ int sdata[256];
  const int tid = threadIdx.x;
  sdata[tid] = (tid < nb) ? bsums[tid] : 0;
  __syncthreads();
  for (int off = 1; off < 256; off <<= 1) {
    int t = (tid >= off) ? sdata[tid - off] : 0;
    __syncthreads();
    sdata[tid] += t;
    __syncthreads();
  }
  const int excl = (tid > 0) ? sdata[tid - 1] : 0;
  if (tid < nb) bsums[tid] = excl;
}

__global__ void k_scan3(int* __restrict__ rowptr, const int* __restrict__ bsums, int n) {
  int i = blockIdx.x * blockDim.x + threadIdx.x;
  if (i < n) rowptr[i] += bsums[i >> 10];
}

__global__ void k_fill(const int* __restrict__ src, const int* __restrict__ dst,
                       const int* __restrict__ rowptr, int* __restrict__ cursor,
                       int* __restrict__ srcs, int e) {
  int i = blockIdx.x * blockDim.x + threadIdx.x;
  if (i < e) {
    const int d = dst[i];
    const int pos = rowptr[d] + atomicAdd(&cursor[d], 1);
    srcs[pos] = src[i];
  }
}

// g(bf16) = (x @ W^T + b) * dinv[r] via mfma_f32_32x32x16_bf16.
// 128x128 tile, whole K=128 staged once as bf16 (one barrier). 4 waves in 2x2,
// each computes 64x64 (2x2 MFMA tiles x 8 K-slices). LDS 64KB -> 2 blocks/CU.
// Frag reads (lane l: row l&31, 16B k-chunk l>>5) would be 32-way bank
// conflicts on linear layout -> XOR-swizzle chunk with (row&7) on BOTH sides.
__global__ __launch_bounds__(256) void k_gemm(
    const float* __restrict__ x, const float* __restrict__ W,
    const float* __restrict__ bias, const float* __restrict__ dinv,
    __hip_bfloat16* __restrict__ g, int n) {
  __shared__ unsigned short xs[128 * 128];
  __shared__ unsigned short Ws[128 * 128];
  const int tid = threadIdx.x;
  const int row0 = blockIdx.x * 128;

#pragma unroll
  for (int u = 0; u < 8; ++u) {
    const int f = tid + 256 * u;      // 0..2047
    const int row = f >> 4;           // 0..127
    const int c = f & 15;             // 16B chunk within row (8 bf16)
    const int ch = (c ^ (row & 7)) << 3;  // swizzled ushort offset
    {  // W tile
      const float4* p = reinterpret_cast<const float4*>(&W[(size_t)row * D + c * 8]);
      const float4 v0 = p[0], v1 = p[1];
      uint4 pk;
      pk.x = f2bf(v0.x) | ((unsigned)f2bf(v0.y) << 16);
      pk.y = f2bf(v0.z) | ((unsigned)f2bf(v0.w) << 16);
      pk.z = f2bf(v1.x) | ((unsigned)f2bf(v1.y) << 16);
      pk.w = f2bf(v1.z) | ((unsigned)f2bf(v1.w) << 16);
      *reinterpret_cast<uint4*>(&Ws[row * 128 + ch]) = pk;
    }
    {  // x tile
      float4 v0 = make_float4(0.f, 0.f, 0.f, 0.f), v1 = v0;
      if (row0 + row < n) {
        const float4* p =
            reinterpret_cast<const float4*>(&x[(size_t)(row0 + row) * D + c * 8]);
        v0 = p[0]; v1 = p[1];
      }
      uint4 pk;
      pk.x = f2bf(v0.x) | ((unsigned)f2bf(v0.y) << 16);
      pk.y = f2bf(v0.z) | ((unsigned)f2bf(v0.w) << 16);
      pk.z = f2bf(v1.x) | ((unsigned)f2bf(v1.y) << 16);
      pk.w = f2bf(v1.z) | ((unsigned)f2bf(v1.w) << 16);
      *reinterpret_cast<uint4*>(&xs[row * 128 + ch]) = pk;
    }
  }
  __syncthreads();

  const int lane = tid & 63;
  const int wv = tid >> 6;
  const int wr = (wv >> 1) * 64;  // wave row offset
  const int wc = (wv & 1) * 64;   // wave col offset
  const int lr = lane & 31;
  const int lk = lane >> 5;       // which 16B k-chunk within a k-slice

  f32x16 acc[2][2];
#pragma unroll
  for (int m = 0; m < 2; ++m)
#pragma unroll
    for (int j = 0; j < 2; ++j)
#pragma unroll
      for (int q = 0; q < 16; ++q) acc[m][j][q] = 0.f;

#pragma unroll
  for (int ks = 0; ks < 8; ++ks) {
    bf16x8 a[2], b[2];
#pragma unroll
    for (int m = 0; m < 2; ++m) {
      const int r = wr + m * 32 + lr;
      const int ch = ((ks * 2 + lk) ^ (r & 7)) << 3;
      a[m] = *reinterpret_cast<const bf16x8*>(&xs[r * 128 + ch]);
    }
#pragma unroll
    for (int j = 0; j < 2; ++j) {
      const int r = wc + j * 32 + lr;
      const int ch = ((ks * 2 + lk) ^ (r & 7)) << 3;
      b[j] = *reinterpret_cast<const bf16x8*>(&Ws[r * 128 + ch]);
    }
#pragma unroll
    for (int m = 0; m < 2; ++m)
#pragma unroll
      for (int j = 0; j < 2; ++j)
        acc[m][j] = __builtin_amdgcn_mfma_f32_32x32x16_bf16(a[m], b[j], acc[m][j], 0, 0, 0);
  }

  // C/D layout (m74/m101): col = lane&31, row = (reg&3) + 8*(reg>>2) + 4*(lane>>5)
#pragma unroll
  for (int m = 0; m < 2; ++m) {
#pragma unroll
    for (int reg = 0; reg < 16; ++reg) {
      const int rloc = (reg & 3) + 8 * (reg >> 2) + 4 * lk;
      const int r = row0 + wr + m * 32 + rloc;
      if (r < n) {
        const float dv = dinv[r];
#pragma unroll
        for (int j = 0; j < 2; ++j) {
          const int col = wc + j * 32 + lr;
          g[(size_t)r * D + col] = __float2bfloat16((acc[m][j][reg] + bias[col]) * dv);
        }
      }
    }
  }
}

// one wave per node: out[v] = dinv[v]*(g[v] + sum g[s]); bf16 g rows (256B/row)
__global__ __launch_bounds__(256) void k_accum(
    const int* __restrict__ rowptr, const int* __restrict__ cnt,
    const int* __restrict__ srcs, const unsigned int* __restrict__ g2,
    const float* __restrict__ dinv, float* __restrict__ out, int n) {
  const int w = (int)(((size_t)blockIdx.x * 256 + threadIdx.x) >> 6);
  const int lane = threadIdx.x & 63;
  if (w >= n) return;
  const int beg = rowptr[w];
  const int num = cnt[w];
  const unsigned int v = g2[(size_t)w * 64 + lane];  // self-loop term
  float ax = __uint_as_float(v << 16);
  float ay = __uint_as_float(v & 0xffff0000u);
  int k = 0;
  for (; k + 8 <= num; k += 8) {
    unsigned int t[8];
#pragma unroll
    for (int u = 0; u < 8; ++u)
      t[u] = g2[(size_t)srcs[beg + k + u] * 64 + lane];
#pragma unroll
    for (int u = 0; u < 8; ++u) {
      ax += __uint_as_float(t[u] << 16);
      ay += __uint_as_float(t[u] & 0xffff0000u);
    }
  }
  for (; k < num; ++k) {
    const unsigned int t = g2[(size_t)srcs[beg + k] * 64 + lane];
    ax += __uint_as_float(t << 16);
    ay += __uint_as_float(t & 0xffff0000u);
  }
  const float dv = dinv[w];
  ((float2*)out)[(size_t)w * 64 + lane] = make_float2(ax * dv, ay * dv);
}

extern "C" void kernel_launch(void* const* d_in, const int* in_sizes, int n_in,
                              void* d_out, int out_size, void* d_ws, size_t ws_size,
                              hipStream_t stream) {
  const float* x = (const float*)d_in[0];
  const int* ei = (const int*)d_in[1];
  const float* W = (const float*)d_in[2];
  const float* b = (const float*)d_in[3];
  float* out = (float*)d_out;
  const int n = in_sizes[0] / D;
  const int e = in_sizes[1] / 2;
  const int* src = ei;      // edge_index[0]
  const int* dst = ei + e;  // edge_index[1]

  char* ws = (char*)d_ws;
  const size_t nb = ((size_t)n * 4 + 255) / 256 * 256;
  const size_t eb = ((size_t)e * 4 + 255) / 256 * 256;
  int* rowptr = (int*)ws;                          // n ints
  int* cnt = (int*)(ws + nb);                      // n ints (in-degree)
  float* dinv = (float*)(ws + 2 * nb);             // n floats
  int* cursor = (int*)(ws + 3 * nb);               // n ints
  int* bsums = (int*)(ws + 4 * nb);                // <=512 ints
  int* srcs = (int*)(ws + 4 * nb + 4096);          // e ints
  __hip_bfloat16* g = (__hip_bfloat16*)(ws + 4 * nb + 4096 + eb);  // n*128 bf16

  const int nscan = (n + 1023) / 1024;

  k_zero<<<(n + 255) / 256, 256, 0, stream>>>(cnt, n);
  k_deg_count<<<(e + 255) / 256, 256, 0, stream>>>(dst, e, cnt);
  k_scan1<<<nscan, 256, 0, stream>>>(cnt, rowptr, bsums, dinv, n);
  k_scan2<<<1, 256, 0, stream>>>(bsums, nscan);
  k_scan3<<<(n + 255) / 256, 256, 0, stream>>>(rowptr, bsums, n);
  k_zero<<<(n + 255) / 256, 256, 0, stream>>>(cursor, n);
  k_gemm<<<(n + 127) / 128, 256, 0, stream>>>(x, W, b, dinv, g, n);
  k_fill<<<(e + 255) / 256, 256, 0, stream>>>(src, dst, rowptr, cursor, srcs, e);
  k_accum<<<(n + 3) / 4, 256, 0, stream>>>(rowptr, cnt, srcs, (const unsigned int*)g,
                                           dinv, out, n);
}